// Round 10
// baseline (424.354 us; speedup 1.0000x reference)
//
#include <hip/hip_runtime.h>
#include <hip/hip_bf16.h>

typedef __attribute__((ext_vector_type(8))) short bf16x8;
typedef __attribute__((ext_vector_type(4))) float f32x4;

__device__ __forceinline__ unsigned short f2b_bits(float x) {
    __hip_bfloat16 h = __float2bfloat16(x);
    unsigned short u;
    __builtin_memcpy(&u, &h, 2);
    return u;
}
__device__ __forceinline__ unsigned int pack2(float a, float b) {
    return (unsigned int)f2b_bits(a) | ((unsigned int)f2b_bits(b) << 16);
}
__device__ __forceinline__ float sx8(unsigned int w, int b) {   // signed byte b of w
    return (float)((int)(w << (24 - 8 * b)) >> 24);
}

// ================= MFMA node GEMM =================
// D[ch][node] = sum_k W[k][ch] * A[node][k]  (A-operand = weights, B-operand = nodes)
// EPI: 0 = f32 out (+bias,+ACT relu) ; 1 = bf16 out (+bias,+ACT)
//      2 = int8 row-quant out + scales + attention dots (HD heads)
//      3 = mu/lv/z VAE epilogue (FOUT=32: tiles 0=mu,1=lv)
template<int FIN, int FOUT, int EPI, int HD, bool ABF, int ACT>
__global__ __launch_bounds__(256) void mfma_k(const void* __restrict__ Av,
                                              const float* __restrict__ W,
                                              const float* __restrict__ W2,
                                              const float* __restrict__ bias,
                                              const float* __restrict__ bias2,
                                              void* __restrict__ outv,
                                              void* __restrict__ out2,
                                              void* __restrict__ out3,
                                              float* __restrict__ scales,
                                              const float* __restrict__ asr,
                                              const float* __restrict__ adr,
                                              float* __restrict__ aso,
                                              float* __restrict__ ado,
                                              const float* __restrict__ epsp,
                                              int n)
{
    constexpr int KE = (FIN < 32) ? 32 : FIN;
    constexpr int KP = KE + 8;
    constexpr int KS = KE / 32;
    constexpr int NT = FOUT / 16;
    __shared__ __align__(16) unsigned short As[64 * KP];
    __shared__ __align__(16) unsigned short Wt[FOUT * KP];

    const int t  = threadIdx.x;
    const int m0 = blockIdx.x * 64;

    for (int idx = t; idx < 64 * (KE / 4); idx += 256) {
        int r  = idx / (KE / 4);
        int c4 = (idx % (KE / 4)) * 4;
        int row = m0 + r;
        unsigned int p0 = 0, p1 = 0;
        if (row < n && c4 < FIN) {
            if constexpr (ABF) {
                uint2 rv = *(const uint2*)((const unsigned short*)Av + (size_t)row * FIN + c4);
                p0 = rv.x; p1 = rv.y;
            } else {
                float4 v = *(const float4*)((const float*)Av + (size_t)row * FIN + c4);
                p0 = pack2(v.x, v.y); p1 = pack2(v.z, v.w);
            }
        }
        *(uint2*)(As + r * KP + c4) = make_uint2(p0, p1);
    }
    for (int idx = t; idx < KE * (FOUT / 4); idx += 256) {
        int k  = idx / (FOUT / 4);
        int c4 = (idx % (FOUT / 4)) * 4;
        float4 v = make_float4(0.f, 0.f, 0.f, 0.f);
        if (k < FIN) {
            if constexpr (EPI == 3) {
                v = (c4 < 16) ? *(const float4*)(W  + (size_t)k * 16 + c4)
                              : *(const float4*)(W2 + (size_t)k * 16 + (c4 - 16));
            } else {
                v = *(const float4*)(W + (size_t)k * FOUT + c4);
            }
        }
        Wt[(c4 + 0) * KP + k] = f2b_bits(v.x);
        Wt[(c4 + 1) * KP + k] = f2b_bits(v.y);
        Wt[(c4 + 2) * KP + k] = f2b_bits(v.z);
        Wt[(c4 + 3) * KP + k] = f2b_bits(v.w);
    }
    __syncthreads();

    const int w   = t >> 6;
    const int l   = t & 63;
    const int l15 = l & 15;
    const int g   = l >> 4;
    const int node = m0 + w * 16 + l15;

    f32x4 acc[NT];
    #pragma unroll
    for (int i = 0; i < NT; ++i) acc[i] = (f32x4){0.f, 0.f, 0.f, 0.f};

    #pragma unroll
    for (int ks = 0; ks < KS; ++ks) {
        bf16x8 nf = *(const bf16x8*)(As + (w * 16 + l15) * KP + ks * 32 + g * 8);
        #pragma unroll
        for (int tt = 0; tt < NT; ++tt) {
            bf16x8 wf = *(const bf16x8*)(Wt + (tt * 16 + l15) * KP + ks * 32 + g * 8);
            acc[tt] = __builtin_amdgcn_mfma_f32_16x16x32_bf16(wf, nf, acc[tt], 0, 0, 0);
        }
    }

    if constexpr (EPI == 0 || EPI == 1) {
        #pragma unroll
        for (int tt = 0; tt < NT; ++tt) {
            float4 bb = *(const float4*)(bias + 16 * tt + 4 * g);
            float o0 = acc[tt][0] + bb.x, o1 = acc[tt][1] + bb.y;
            float o2 = acc[tt][2] + bb.z, o3 = acc[tt][3] + bb.w;
            if (ACT == 1) {
                o0 = fmaxf(o0, 0.f); o1 = fmaxf(o1, 0.f);
                o2 = fmaxf(o2, 0.f); o3 = fmaxf(o3, 0.f);
            }
            if (node < n) {
                if constexpr (EPI == 0) {
                    *(float4*)((float*)outv + (size_t)node * FOUT + 16 * tt + 4 * g) =
                        make_float4(o0, o1, o2, o3);
                } else {
                    *(uint2*)((unsigned short*)outv + (size_t)node * FOUT + 16 * tt + 4 * g) =
                        make_uint2(pack2(o0, o1), pack2(o2, o3));
                }
            }
        }
    } else if constexpr (EPI == 2) {
        float amax = 0.f;
        float dsh[HD], ddh[HD];
        #pragma unroll
        for (int h = 0; h < HD; ++h) { dsh[h] = 0.f; ddh[h] = 0.f; }
        #pragma unroll
        for (int tt = 0; tt < NT; ++tt) {
            float4 av = *(const float4*)(asr + 16 * tt + 4 * g);
            float4 dv = *(const float4*)(adr + 16 * tt + 4 * g);
            const float* avp = (const float*)&av;
            const float* dvp = (const float*)&dv;
            const int h = (HD == 2) ? (tt / (NT / 2)) : 0;
            #pragma unroll
            for (int j = 0; j < 4; ++j) {
                float xv = acc[tt][j];
                amax = fmaxf(amax, fabsf(xv));
                dsh[h] = fmaf(xv, avp[j], dsh[h]);
                ddh[h] = fmaf(xv, dvp[j], ddh[h]);
            }
        }
        amax = fmaxf(amax, __shfl_xor(amax, 16, 64));
        amax = fmaxf(amax, __shfl_xor(amax, 32, 64));
        #pragma unroll
        for (int h = 0; h < HD; ++h) {
            dsh[h] += __shfl_xor(dsh[h], 16, 64);
            dsh[h] += __shfl_xor(dsh[h], 32, 64);
            ddh[h] += __shfl_xor(ddh[h], 16, 64);
            ddh[h] += __shfl_xor(ddh[h], 32, 64);
        }
        float invsc = amax > 0.f ? 127.f / amax : 0.f;
        if (node < n) {
            #pragma unroll
            for (int tt = 0; tt < NT; ++tt) {
                int q0 = __float2int_rn(acc[tt][0] * invsc);
                int q1 = __float2int_rn(acc[tt][1] * invsc);
                int q2 = __float2int_rn(acc[tt][2] * invsc);
                int q3 = __float2int_rn(acc[tt][3] * invsc);
                unsigned int pv = (q0 & 255) | ((q1 & 255) << 8) |
                                  ((q2 & 255) << 16) | ((q3 & 255) << 24);
                ((unsigned int*)outv)[(size_t)node * (FOUT / 4) + 4 * tt + g] = pv;
            }
            if (g == 0) {
                scales[node] = amax * (1.f / 127.f);
                #pragma unroll
                for (int h = 0; h < HD; ++h) {
                    aso[(size_t)node * HD + h] = dsh[h];
                    ado[(size_t)node * HD + h] = ddh[h];
                }
            }
        }
    } else {   // EPI == 3
        float4 mb = *(const float4*)(bias  + 4 * g);
        float4 lb = *(const float4*)(bias2 + 4 * g);
        float mu0 = acc[0][0] + mb.x, mu1 = acc[0][1] + mb.y;
        float mu2 = acc[0][2] + mb.z, mu3 = acc[0][3] + mb.w;
        float lv0 = acc[1][0] + lb.x, lv1 = acc[1][1] + lb.y;
        float lv2 = acc[1][2] + lb.z, lv3 = acc[1][3] + lb.w;
        if (node < n) {
            float4 ep = *(const float4*)(epsp + (size_t)node * 16 + 4 * g);
            float z0 = fmaf(ep.x, __expf(0.5f * fminf(fmaxf(lv0, -10.f), 10.f)), mu0);
            float z1 = fmaf(ep.y, __expf(0.5f * fminf(fmaxf(lv1, -10.f), 10.f)), mu1);
            float z2 = fmaf(ep.z, __expf(0.5f * fminf(fmaxf(lv2, -10.f), 10.f)), mu2);
            float z3 = fmaf(ep.w, __expf(0.5f * fminf(fmaxf(lv3, -10.f), 10.f)), mu3);
            *(float4*)((float*)outv + (size_t)node * 16 + 4 * g) = make_float4(mu0, mu1, mu2, mu3);
            *(float4*)((float*)out2 + (size_t)node * 16 + 4 * g) = make_float4(lv0, lv1, lv2, lv3);
            *(uint2*)((unsigned short*)out3 + (size_t)node * 16 + 4 * g) =
                make_uint2(pack2(z0, z1), pack2(z2, z3));
        }
    }
}

// ---------------- CSR build (band-major within dst: key = d*8 + (src>>bshift)) ----------------
__global__ __launch_bounds__(256) void count_k(const int* __restrict__ ei, int* __restrict__ cnt,
                                               int E, int bshift)
{
    int e = blockIdx.x * 256 + threadIdx.x;
    if (e >= E) return;
    int s = ei[e], d = ei[E + e];
    atomicAdd(&cnt[d * 8 + (s >> bshift)], 1);
}

__global__ __launch_bounds__(256) void scanA_k(const int* __restrict__ cnt, int* __restrict__ incl,
                                               int* __restrict__ bsum, int m)
{
    __shared__ int sh[256];
    int i = blockIdx.x * 256 + threadIdx.x;
    int v = (i < m) ? cnt[i] : 0;
    sh[threadIdx.x] = v;
    __syncthreads();
    #pragma unroll
    for (int o = 1; o < 256; o <<= 1) {
        int t = (threadIdx.x >= o) ? sh[threadIdx.x - o] : 0;
        __syncthreads();
        sh[threadIdx.x] += t;
        __syncthreads();
    }
    if (i < m) incl[i] = sh[threadIdx.x];
    if (threadIdx.x == 255) bsum[blockIdx.x] = sh[255];
}

// looping single-block exclusive scan of block sums (nb may exceed 512)
__global__ __launch_bounds__(512) void scanB_k(int* __restrict__ bsum, int nb)
{
    __shared__ int sh[512];
    __shared__ int carrysh;
    if (threadIdx.x == 0) carrysh = 0;
    __syncthreads();
    for (int base = 0; base < nb; base += 512) {
        int i = base + threadIdx.x;
        int v = (i < nb) ? bsum[i] : 0;
        sh[threadIdx.x] = v;
        __syncthreads();
        #pragma unroll
        for (int o = 1; o < 512; o <<= 1) {
            int t = (threadIdx.x >= o) ? sh[threadIdx.x - o] : 0;
            __syncthreads();
            sh[threadIdx.x] += t;
            __syncthreads();
        }
        int c = carrysh;
        if (i < nb) bsum[i] = c + sh[threadIdx.x] - v;   // exclusive
        __syncthreads();
        if (threadIdx.x == 511) carrysh = c + sh[511];
        __syncthreads();
    }
}

__global__ __launch_bounds__(256) void scanC_k(const int* __restrict__ cnt, const int* __restrict__ incl,
                                               const int* __restrict__ bsum, int* __restrict__ off,
                                               int* __restrict__ cursor, int m, int E)
{
    int i = blockIdx.x * 256 + threadIdx.x;
    if (i >= m) return;
    int v = incl[i] - cnt[i] + bsum[i >> 8];
    off[i] = v;
    cursor[i] = v;
    if (i == 0) off[m] = E;
}

// dst-range-partitioned scatter (write-combining within one XCD's L2 per range)
__global__ __launch_bounds__(256) void scatter_k(const int* __restrict__ ei, int* __restrict__ cursor,
                                                 int* __restrict__ csr_src, int E, int n, int bshift)
{
    const int grp = blockIdx.x & 7;
    const int bin = blockIdx.x >> 3;
    const int bpg = gridDim.x >> 3;
    const int rsz = (n + 7) >> 3;
    const int lo = grp * rsz;
    const int hi = min(n, lo + rsz);
    const int stride = bpg * 256;
    for (int e = bin * 256 + threadIdx.x; e < E; e += stride) {
        int d = ei[E + e];
        if (d >= lo && d < hi) {
            int s = ei[e];
            int pos = atomicAdd(&cursor[d * 8 + (s >> bshift)], 1);
            csr_src[pos] = s;
        }
    }
}

// ---------------- fused per-dst softmax + aggregate (int8 h; band-major edge order) ----------------
template<int FEAT, int H, int ACT, bool OUTB>
__global__ __launch_bounds__(256) void gat_agg_k(const int* __restrict__ csr_src,
                                                 const int* __restrict__ off,
                                                 const float* __restrict__ as_,
                                                 const float* __restrict__ ad_,
                                                 const unsigned int* __restrict__ h8,
                                                 const float* __restrict__ sc,
                                                 const float* __restrict__ bias,
                                                 void* __restrict__ outv, int n)
{
    constexpr int LANES = 16;
    constexpr int FPL   = FEAT / LANES;
    constexpr int WPR   = FEAT / 4;
    constexpr int SUBL  = LANES / H;
    constexpr int NCH   = 4;
    const int tid = blockIdx.x * 256 + threadIdx.x;
    const int d = tid >> 4;
    if (d >= n) return;
    const int lane = threadIdx.x & 15;
    const int myhead = lane / SUBL;
    const int sl = lane % SUBL;
    const int start = off[d * 8], end = off[d * 8 + 8];
    const float adm = ad_[d * H + myhead];

    float vreg[NCH], sreg_sc[NCH]; int sreg[NCH];
    float m = -3.4e38f;
    #pragma unroll
    for (int c = 0; c < NCH; ++c) {
        int j = start + sl + c * SUBL;
        int s = 0; float v = -3.4e38f, scl = 0.f;
        if (j < end) {
            s = csr_src[j];
            v = as_[s * H + myhead] + adm;
            v = v > 0.f ? v : 0.2f * v;
            scl = sc[s];
        }
        sreg[c] = s; vreg[c] = v; sreg_sc[c] = scl;
        m = fmaxf(m, v);
    }
    for (int j = start + sl + NCH * SUBL; j < end; j += SUBL) {
        int s = csr_src[j];
        float v = as_[s * H + myhead] + adm;
        v = v > 0.f ? v : 0.2f * v;
        m = fmaxf(m, v);
    }
    #pragma unroll
    for (int o = SUBL / 2; o > 0; o >>= 1)
        m = fmaxf(m, __shfl_xor(m, o, SUBL));

    float ssum = 0.f;
    #pragma unroll
    for (int c = 0; c < NCH; ++c)
        if (start + sl + c * SUBL < end) ssum += __expf(vreg[c] - m);
    for (int j = start + sl + NCH * SUBL; j < end; j += SUBL) {
        int s = csr_src[j];
        float v = as_[s * H + myhead] + adm;
        v = v > 0.f ? v : 0.2f * v;
        ssum += __expf(v - m);
    }
    #pragma unroll
    for (int o = SUBL / 2; o > 0; o >>= 1)
        ssum += __shfl_xor(ssum, o, SUBL);
    const float inv = 1.f / (ssum + 1e-16f);

    float acc[FPL];
    #pragma unroll
    for (int k = 0; k < FPL; ++k) acc[k] = 0.f;

    auto body = [&](float a, int s) {
        if constexpr (FPL == 8) {
            uint2 r = ((const uint2*)(h8 + (size_t)s * WPR))[lane];
            acc[0] = fmaf(sx8(r.x, 0), a, acc[0]);
            acc[1] = fmaf(sx8(r.x, 1), a, acc[1]);
            acc[2] = fmaf(sx8(r.x, 2), a, acc[2]);
            acc[3] = fmaf(sx8(r.x, 3), a, acc[3]);
            acc[4] = fmaf(sx8(r.y, 0), a, acc[4]);
            acc[5] = fmaf(sx8(r.y, 1), a, acc[5]);
            acc[6] = fmaf(sx8(r.y, 2), a, acc[6]);
            acc[7] = fmaf(sx8(r.y, 3), a, acc[7]);
        } else {
            unsigned int r = (h8 + (size_t)s * WPR)[lane];
            acc[0] = fmaf(sx8(r, 0), a, acc[0]);
            acc[1] = fmaf(sx8(r, 1), a, acc[1]);
            acc[2] = fmaf(sx8(r, 2), a, acc[2]);
            acc[3] = fmaf(sx8(r, 3), a, acc[3]);
        }
    };

    const int nch = (end - start + SUBL - 1) / SUBL;
    for (int c = 0; c < nch; ++c) {
        const int j0 = start + c * SUBL;
        const int cnt = min(SUBL, end - j0);
        float myalpha = 0.f; int mysrc = 0;
        if (c < NCH) {
            mysrc = sreg[c];
            if (sl < cnt) myalpha = __expf(vreg[c] - m) * inv * sreg_sc[c];
        } else {
            if (sl < cnt) {
                mysrc = csr_src[j0 + sl];
                float v = as_[mysrc * H + myhead] + adm;
                v = v > 0.f ? v : 0.2f * v;
                myalpha = __expf(v - m) * inv * sc[mysrc];
            }
        }
        if (cnt == SUBL) {
            #pragma unroll
            for (int u = 0; u < SUBL; ++u) {
                float a = __shfl(myalpha, myhead * SUBL + u, LANES);
                int   s = __shfl(mysrc, u, LANES);
                body(a, s);
            }
        } else {
            for (int u = 0; u < cnt; ++u) {
                float a = __shfl(myalpha, myhead * SUBL + u, LANES);
                int   s = __shfl(mysrc, u, LANES);
                body(a, s);
            }
        }
    }

    if constexpr (OUTB) {
        float o[FPL];
        #pragma unroll
        for (int k = 0; k < FPL; ++k) {
            o[k] = acc[k] + bias[lane * FPL + k];
            if (ACT == 1) o[k] = fmaxf(o[k], 0.f);
        }
        uint4 pv;
        pv.x = pack2(o[0], o[1]); pv.y = pack2(o[2], o[3]);
        pv.z = pack2(o[4], o[5]); pv.w = pack2(o[6], o[7]);
        *(uint4*)((unsigned short*)outv + (size_t)d * FEAT + lane * FPL) = pv;
    } else {
        float* outf = (float*)outv;
        #pragma unroll
        for (int k = 0; k < FPL; ++k) {
            float o = acc[k] + bias[lane * FPL + k];
            if (ACT == 1) o = fmaxf(o, 0.f);
            outf[(size_t)d * FEAT + lane * FPL + k] = o;
        }
    }
}

// ---------------- launch ----------------
extern "C" void kernel_launch(void* const* d_in, const int* in_sizes, int n_in,
                              void* d_out, int out_size, void* d_ws, size_t ws_size,
                              hipStream_t stream)
{
    const int n = in_sizes[0] / 128;     // N nodes
    const int E = in_sizes[1] / 2;       // edges
    const int m8 = n * 8;                // (dst, band) keys

    int bshift = 0;
    while (((n - 1) >> bshift) >= 8) ++bshift;   // band = src >> bshift in [0,8)

    const float* x   = (const float*)d_in[0];
    const int*   ei  = (const int*)d_in[1];
    const float* eps = (const float*)d_in[3];
    const float* W1  = (const float*)d_in[4];
    const float* as1w= (const float*)d_in[5];
    const float* ad1w= (const float*)d_in[6];
    const float* b1  = (const float*)d_in[7];
    const float* W2  = (const float*)d_in[8];
    const float* as2w= (const float*)d_in[9];
    const float* ad2w= (const float*)d_in[10];
    const float* b2  = (const float*)d_in[11];
    const float* fc1w= (const float*)d_in[12];
    const float* fc1b= (const float*)d_in[13];
    const float* muw = (const float*)d_in[14];
    const float* mub = (const float*)d_in[15];
    const float* lvw = (const float*)d_in[16];
    const float* lvb = (const float*)d_in[17];
    const float* fc3w= (const float*)d_in[18];
    const float* fc3b= (const float*)d_in[19];
    const float* fc4w= (const float*)d_in[20];
    const float* fc4b= (const float*)d_in[21];

    char* ws = (char*)d_ws;

    size_t oCnt   = 0;                               // int [8n]  (memset)
    size_t oOff   = oCnt  + (size_t)m8 * 4;          // int [8n+1]
    size_t oIncl  = oOff  + (size_t)(m8 + 1) * 4;
    size_t oCur   = oIncl + (size_t)m8 * 4;
    size_t oBsum  = oCur  + (size_t)m8 * 4;          // int [4096]
    size_t oCsr   = oBsum + 4096 * 4;
    size_t oR1    = oCsr  + (size_t)E * 4;           // h1q int8[n,128] -> h1v bf16[n,128]
    size_t oR2    = oR1   + (size_t)n * 256;         // hl2b bf16[n,128] -> h3 bf16[n,128]
    size_t oR3    = oR2   + (size_t)n * 256;         // h2q int8[n,64] -> zb bf16[n,16]
    size_t oAS1   = oR3   + (size_t)n * 128;
    size_t oAD1   = oAS1  + (size_t)n * 2 * 4;
    size_t oAS2   = oAD1  + (size_t)n * 2 * 4;
    size_t oAD2   = oAS2  + (size_t)n * 4;
    size_t oSC1   = oAD2  + (size_t)n * 4;
    size_t oSC2   = oSC1  + (size_t)n * 4;
    (void)oSC2;

    int* cnt    = (int*)(ws + oCnt);
    int* off    = (int*)(ws + oOff);
    int* incl   = (int*)(ws + oIncl);
    int* cursor = (int*)(ws + oCur);
    int* bsum   = (int*)(ws + oBsum);
    int* csr    = (int*)(ws + oCsr);
    unsigned int*   h1q  = (unsigned int*)(ws + oR1);
    unsigned short* h1v  = (unsigned short*)(ws + oR1);
    unsigned short* hl2b = (unsigned short*)(ws + oR2);
    unsigned short* h3   = (unsigned short*)(ws + oR2);
    unsigned int*   h2q  = (unsigned int*)(ws + oR3);
    unsigned short* zb   = (unsigned short*)(ws + oR3);
    float* as1  = (float*)(ws + oAS1);
    float* ad1  = (float*)(ws + oAD1);
    float* as2  = (float*)(ws + oAS2);
    float* ad2  = (float*)(ws + oAD2);
    float* sc1  = (float*)(ws + oSC1);
    float* sc2  = (float*)(ws + oSC2);

    float* out     = (float*)d_out;
    float* o_recon = out;
    float* o_mu    = out + (size_t)n * 64;
    float* o_lv    = out + (size_t)n * 80;
    float* o_gat   = out + (size_t)n * 96;

    const int ebl  = (E + 255) / 256;
    const int nbS8 = (m8 + 255) / 256;
    const int abl  = (n * 16 + 255) / 256;
    const int g64  = (n + 63) / 64;

    // --- band-major CSR build ---
    hipMemsetAsync(cnt, 0, (size_t)m8 * 4, stream);
    count_k<<<ebl, 256, 0, stream>>>(ei, cnt, E, bshift);
    scanA_k<<<nbS8, 256, 0, stream>>>(cnt, incl, bsum, m8);
    scanB_k<<<1, 512, 0, stream>>>(bsum, nbS8);
    scanC_k<<<nbS8, 256, 0, stream>>>(cnt, incl, bsum, off, cursor, m8, E);
    scatter_k<<<1024, 256, 0, stream>>>(ei, cursor, csr, E, n, bshift);

    // --- GAT layer 1: MFMA GEMM -> int8 h1 (+dots+scales), agg -> bf16 hl2 ---
    mfma_k<128, 128, 2, 2, false, 0><<<g64, 256, 0, stream>>>(
        x, W1, nullptr, nullptr, nullptr, h1q, nullptr, nullptr,
        sc1, as1w, ad1w, as1, ad1, nullptr, n);
    gat_agg_k<128, 2, 1, true><<<abl, 256, 0, stream>>>(
        csr, off, as1, ad1, h1q, sc1, b1, hl2b, n);

    // --- GAT layer 2: MFMA GEMM (bf16 A) -> int8 h2 (+dots), agg -> f32 o_gat ---
    mfma_k<128, 64, 2, 1, true, 0><<<g64, 256, 0, stream>>>(
        hl2b, W2, nullptr, nullptr, nullptr, h2q, nullptr, nullptr,
        sc2, as2w, ad2w, as2, ad2, nullptr, n);
    gat_agg_k<64, 1, 0, false><<<abl, 256, 0, stream>>>(
        csr, off, as2, ad2, h2q, sc2, b2, o_gat, n);

    // --- VAE ---
    mfma_k<64, 128, 1, 0, false, 1><<<g64, 256, 0, stream>>>(
        o_gat, fc1w, nullptr, fc1b, nullptr, h1v, nullptr, nullptr,
        nullptr, nullptr, nullptr, nullptr, nullptr, nullptr, n);
    mfma_k<128, 32, 3, 0, true, 0><<<g64, 256, 0, stream>>>(
        h1v, muw, lvw, mub, lvb, o_mu, o_lv, zb,
        nullptr, nullptr, nullptr, nullptr, nullptr, eps, n);
    mfma_k<16, 128, 1, 0, true, 1><<<g64, 256, 0, stream>>>(
        zb, fc3w, nullptr, fc3b, nullptr, h3, nullptr, nullptr,
        nullptr, nullptr, nullptr, nullptr, nullptr, nullptr, n);
    mfma_k<128, 64, 0, 0, true, 0><<<g64, 256, 0, stream>>>(
        h3, fc4w, nullptr, fc4b, nullptr, o_recon, nullptr, nullptr,
        nullptr, nullptr, nullptr, nullptr, nullptr, nullptr, n);
}